// Round 3
// baseline (172.123 us; speedup 1.0000x reference)
//
#include <hip/hip_runtime.h>
#include <hip/hip_bf16.h>
#include <math.h>

// Bidirectional cross-attention (B=8, L=2048, D=128, fp32 in/out).
// v3: prepass converts inputs to bf16 hi/lo planes + transposed-hi plane in
// d_ws; main kernel is a one-pass flash with global_load_lds staging
// (source-swizzled, linear LDS), raw barriers + counted vmcnt, setprio.

#define LSEQ 2048
#define DIM  128
#define NBATCH 8
#define BM 128          // X rows per block
#define BJ 64           // j-tile
#define NJT (LSEQ / BJ) // 32
#define PADD (DIM + 8)  // fallback kernel only
#define PADJ (BJ + 8)   // 72 shorts per row (Pt)
#define VROW 72         // fallback kernel only
#define THR_DEFER 8.0f
#define PLANE (NBATCH * LSEQ * DIM)   // 2097152 elems (4 MiB as bf16)

typedef short v8s __attribute__((ext_vector_type(8)));
typedef float v4f __attribute__((ext_vector_type(4)));

__device__ __forceinline__ short f2bf(float f) {
    union { float f; unsigned u; } v; v.f = f;
    unsigned r = (v.u + 0x7FFFu + ((v.u >> 16) & 1u)) >> 16;
    return (short)r;
}
__device__ __forceinline__ float bf2f(short s) {
    union { float f; unsigned u; } v;
    v.u = ((unsigned)(unsigned short)s) << 16;
    return v.f;
}

__device__ __forceinline__ void gload16(const void* g, void* l) {
    __builtin_amdgcn_global_load_lds(
        (const __attribute__((address_space(1))) unsigned int*)g,
        (__attribute__((address_space(3))) unsigned int*)l, 16, 0, 0);
}

// ---------------- prepass: fp32 -> {hi, lo, tr-hi} bf16 planes ----------------
__global__ __launch_bounds__(256, 4)
void prepass_kernel(const float* __restrict__ S1, const float* __restrict__ S2,
                    short* __restrict__ ws)
{
    __shared__ short Th[DIM][66];   // transposed hi tile [d][r], pad 66 (2-way)
    const int lt = blockIdx.x;      // l-tile (64 rows)
    const int bb = blockIdx.y;
    const int tn = blockIdx.z;      // tensor 0=S1, 1=S2
    const float* src = (tn ? S2 : S1) + ((size_t)bb * LSEQ + (size_t)lt * 64) * DIM;
    short* hi = ws + (size_t)tn * 3 * PLANE + ((size_t)bb * LSEQ + (size_t)lt * 64) * DIM;
    short* lo = hi + PLANE;
    short* tr = ws + (size_t)tn * 3 * PLANE + 2 * (size_t)PLANE
              + (size_t)bb * DIM * LSEQ + (size_t)lt * 64;
    const int tid = threadIdx.x;
    #pragma unroll
    for (int it = 0; it < 8; ++it) {
        int idx = tid + it * 256;       // 2048 float4 = 64x128 floats
        int r = idx >> 5;               // 0..63
        int c = (idx & 31) * 4;         // 0..124
        float4 v = *(const float4*)(src + (size_t)r * DIM + c);
        short h0 = f2bf(v.x), h1 = f2bf(v.y), h2 = f2bf(v.z), h3 = f2bf(v.w);
        short q0 = f2bf(v.x - bf2f(h0)), q1 = f2bf(v.y - bf2f(h1));
        short q2 = f2bf(v.z - bf2f(h2)), q3 = f2bf(v.w - bf2f(h3));
        *(short4*)&hi[(size_t)r * DIM + c] = make_short4(h0, h1, h2, h3);
        *(short4*)&lo[(size_t)r * DIM + c] = make_short4(q0, q1, q2, q3);
        Th[c + 0][r] = h0; Th[c + 1][r] = h1;
        Th[c + 2][r] = h2; Th[c + 3][r] = h3;
    }
    __syncthreads();
    #pragma unroll
    for (int it = 0; it < 16; ++it) {
        int idx = tid + it * 256;       // 128x32 ints
        int d = idx >> 5;
        int c = (idx & 31) * 2;
        unsigned val = (unsigned)(unsigned short)Th[d][c]
                     | ((unsigned)(unsigned short)Th[d][c + 1] << 16);
        *(unsigned*)(tr + (size_t)d * LSEQ + c) = val;
    }
}

// ---------------- main flash kernel ----------------
__global__ __launch_bounds__(512, 2)
void xattn_main(const short* __restrict__ ws, float* __restrict__ out)
{
    __shared__ short YhL[2][BJ * DIM];   // [64][128] linear (swizzled content)
    __shared__ short YlL[2][BJ * DIM];
    __shared__ short VtL[2][DIM * BJ];   // [128][64] linear (swizzled content)
    __shared__ short Pt[BM][PADJ];
    __shared__ float maxpart[4][BM];
    __shared__ float spart[4][BM];
    __shared__ float runm[BM], runs[BM], fac[BM];

    const int tid  = threadIdx.x;
    const int lane = tid & 63;
    const int wave = tid >> 6;      // 0..7
    const int l15  = lane & 15;
    const int lg   = lane >> 4;     // 0..3
    const int wj   = wave & 3;      // E grid: j-slice of 16
    const int wi   = wave >> 2;     // E grid: i-half of 64
    const int wi2  = wave >> 1;     // PV grid: i-quarter of 32
    const int wd   = wave & 1;      // PV grid: d-half of 64

    const int bx   = blockIdx.x;
    const int xcd  = bx & 7;
    const int slot = bx >> 3;
    const int g    = xcd * 2 + (slot >> 4);
    const int rt   = slot & 15;
    const int side = g >> 3;
    const int bb   = g & 7;
    const int tx   = side;          // X tensor plane index
    const int ty   = side ^ 1;

    const short* XH = ws + (size_t)tx * 3 * PLANE + ((size_t)bb * LSEQ + (size_t)rt * BM) * DIM;
    const short* XL = XH + PLANE;
    const short* YH = ws + (size_t)ty * 3 * PLANE + (size_t)bb * LSEQ * DIM;
    const short* YL = YH + PLANE;
    const short* YT = ws + (size_t)ty * 3 * PLANE + 2 * (size_t)PLANE + (size_t)bb * DIM * LSEQ;
    float* O = out + (size_t)side * PLANE + ((size_t)bb * LSEQ + (size_t)rt * BM) * DIM;

    // ---- X fragments -> regs (pre-split planes; no conversion) ----
    v8s xh[4][4], xl[4][4];
    #pragma unroll
    for (int fi = 0; fi < 4; ++fi) {
        const size_t row = (size_t)(wi * 64 + fi * 16 + l15);
        #pragma unroll
        for (int ks = 0; ks < 4; ++ks) {
            const int col = ks * 32 + lg * 8;
            xh[fi][ks] = *(const v8s*)(XH + row * DIM + col);
            xl[fi][ks] = *(const v8s*)(XL + row * DIM + col);
        }
    }

    if (tid < BM) { runm[tid] = -INFINITY; runs[tid] = 0.f; }

    // 48 gload_lds per tile, 6 per wave; source swizzled, LDS linear.
    auto STAGE = [&](int jt, int b) {
        #pragma unroll
        for (int k = 0; k < 6; ++k) {
            const int q = wave * 6 + k;
            if (q < 16) {                       // Yh: 4 rows per instr
                const int r  = q * 4 + (lane >> 4);
                const int c2 = ((lane & 15) * 16) ^ ((r & 7) << 4);
                gload16((const char*)YH + ((size_t)(jt * BJ + r)) * 256 + c2,
                        (char*)&YhL[b][0] + q * 1024);
            } else if (q < 32) {                // Yl
                const int qq = q - 16;
                const int r  = qq * 4 + (lane >> 4);
                const int c2 = ((lane & 15) * 16) ^ ((r & 7) << 4);
                gload16((const char*)YL + ((size_t)(jt * BJ + r)) * 256 + c2,
                        (char*)&YlL[b][0] + qq * 1024);
            } else {                            // Vt: 8 d-rows per instr
                const int qq = q - 32;
                const int d  = qq * 8 + (lane >> 3);
                const int c2 = ((lane & 7) * 16) ^ ((d & 7) << 4);
                gload16((const char*)YT + (size_t)d * (LSEQ * 2) + (size_t)jt * (BJ * 2) + c2,
                        (char*)&VtL[b][0] + qq * 1024);
            }
        }
    };

    STAGE(0, 0);
    __syncthreads();    // prologue: full drain once (tile 0 + X + stats init)

    v4f acc[2][4];
    #pragma unroll
    for (int fm = 0; fm < 2; ++fm)
        #pragma unroll
        for (int fd = 0; fd < 4; ++fd)
            acc[fm][fd] = (v4f){0.f, 0.f, 0.f, 0.f};

    for (int jt = 0; jt < NJT; ++jt) {
        const int cur = jt & 1;
        if (jt + 1 < NJT) {
            STAGE(jt + 1, cur ^ 1);
            asm volatile("s_waitcnt vmcnt(6)" ::: "memory");  // tile jt done; 6 in flight
        } else {
            asm volatile("s_waitcnt vmcnt(0)" ::: "memory");
        }
        __builtin_amdgcn_s_barrier();   // B: buf[cur] ready

        // ---- E^T = Y X^T, 3-pass hi/lo split; wave: j16 (wj) x i64 (wi) ----
        v4f e[4];
        #pragma unroll
        for (int fi = 0; fi < 4; ++fi) e[fi] = (v4f){0.f, 0.f, 0.f, 0.f};
        const int jr = wj * 16 + l15;
        __builtin_amdgcn_s_setprio(1);
        #pragma unroll
        for (int ks = 0; ks < 4; ++ks) {
            const int c2 = (ks * 64 + lg * 16) ^ ((jr & 7) << 4);
            v8s yh = *(const v8s*)((const char*)&YhL[cur][0] + jr * 256 + c2);
            v8s yl = *(const v8s*)((const char*)&YlL[cur][0] + jr * 256 + c2);
            #pragma unroll
            for (int fi = 0; fi < 4; ++fi) {
                e[fi] = __builtin_amdgcn_mfma_f32_16x16x32_bf16(yh, xh[fi][ks], e[fi], 0, 0, 0);
                e[fi] = __builtin_amdgcn_mfma_f32_16x16x32_bf16(yh, xl[fi][ks], e[fi], 0, 0, 0);
                e[fi] = __builtin_amdgcn_mfma_f32_16x16x32_bf16(yl, xh[fi][ks], e[fi], 0, 0, 0);
            }
        }
        __builtin_amdgcn_s_setprio(0);

        // ---- per-row (i) tile-max partials over this wave's j16 ----
        #pragma unroll
        for (int fi = 0; fi < 4; ++fi) {
            float m = fmaxf(fmaxf(e[fi][0], e[fi][1]), fmaxf(e[fi][2], e[fi][3]));
            m = fmaxf(m, __shfl_xor(m, 16));
            m = fmaxf(m, __shfl_xor(m, 32));
            if (lg == 0) maxpart[wj][wi * 64 + fi * 16 + l15] = m;
        }
        asm volatile("s_waitcnt lgkmcnt(0)" ::: "memory");
        __builtin_amdgcn_s_barrier();   // C

        if (tid < BM) {
            float rs = runs[tid];
            if (jt > 0) rs += (spart[0][tid] + spart[1][tid]) + (spart[2][tid] + spart[3][tid]);
            float mt = fmaxf(fmaxf(maxpart[0][tid], maxpart[1][tid]),
                             fmaxf(maxpart[2][tid], maxpart[3][tid]));
            float mo = runm[tid];
            float f = 1.0f;
            if (mt > mo + THR_DEFER) { f = __expf(mo - mt); runm[tid] = mt; rs *= f; }
            fac[tid] = f;
            runs[tid] = rs;
        }
        asm volatile("s_waitcnt lgkmcnt(0)" ::: "memory");
        __builtin_amdgcn_s_barrier();   // D

        // ---- acc rescale (rare: defer-max) ----
        {
            float fr[2][4];
            bool need = false;
            #pragma unroll
            for (int fm = 0; fm < 2; ++fm)
                #pragma unroll
                for (int rg = 0; rg < 4; ++rg) {
                    fr[fm][rg] = fac[wi2 * 32 + fm * 16 + lg * 4 + rg];
                    need = need || (fr[fm][rg] != 1.0f);
                }
            if (__any(need)) {
                #pragma unroll
                for (int fm = 0; fm < 2; ++fm)
                    #pragma unroll
                    for (int fd = 0; fd < 4; ++fd)
                        #pragma unroll
                        for (int rg = 0; rg < 4; ++rg)
                            acc[fm][fd][rg] *= fr[fm][rg];
            }
        }

        // ---- P = exp(E-m) -> Pt, s-partials ----
        #pragma unroll
        for (int fi = 0; fi < 4; ++fi) {
            const int ic = wi * 64 + fi * 16 + l15;
            const float m = runm[ic];
            float p0 = __expf(e[fi][0] - m);
            float p1 = __expf(e[fi][1] - m);
            float p2 = __expf(e[fi][2] - m);
            float p3 = __expf(e[fi][3] - m);
            float s = (p0 + p1) + (p2 + p3);
            s += __shfl_xor(s, 16);
            s += __shfl_xor(s, 32);
            if (lg == 0) spart[wj][ic] = s;
            *(short4*)&Pt[ic][wj * 16 + lg * 4] =
                make_short4(f2bf(p0), f2bf(p1), f2bf(p2), f2bf(p3));
        }
        asm volatile("s_waitcnt lgkmcnt(0)" ::: "memory");
        __builtin_amdgcn_s_barrier();   // E: Pt ready

        // ---- PV: acc[i][d] += P[i][j] * Y[j][d]; wave: i32 (wi2) x d64 (wd) ----
        __builtin_amdgcn_s_setprio(1);
        #pragma unroll
        for (int ks = 0; ks < 2; ++ks) {
            const int k0 = ks * 32 + lg * 8;
            v8s pa[2], vb[4];
            #pragma unroll
            for (int fm = 0; fm < 2; ++fm)
                pa[fm] = *(const v8s*)&Pt[wi2 * 32 + fm * 16 + l15][k0];
            #pragma unroll
            for (int fd = 0; fd < 4; ++fd) {
                const int d = wd * 64 + fd * 16 + l15;
                vb[fd] = *(const v8s*)((const char*)&VtL[cur][0] + d * 128 + ((k0 * 2) ^ ((d & 7) << 4)));
            }
            #pragma unroll
            for (int fm = 0; fm < 2; ++fm)
                #pragma unroll
                for (int fd = 0; fd < 4; ++fd)
                    acc[fm][fd] = __builtin_amdgcn_mfma_f32_16x16x32_bf16(pa[fm], vb[fd], acc[fm][fd], 0, 0, 0);
        }
        __builtin_amdgcn_s_setprio(0);
        __builtin_amdgcn_s_barrier();   // F: all done with buf[cur] & Pt
    }

    if (tid < BM)
        fac[tid] = 1.0f / (runs[tid] + (spart[0][tid] + spart[1][tid]) + (spart[2][tid] + spart[3][tid]));
    __syncthreads();

    #pragma unroll
    for (int fm = 0; fm < 2; ++fm)
        #pragma unroll
        for (int rg = 0; rg < 4; ++rg) {
            const int ir = wi2 * 32 + fm * 16 + lg * 4 + rg;
            const float inv = fac[ir];
            float* orow = O + (size_t)ir * DIM;
            #pragma unroll
            for (int fd = 0; fd < 4; ++fd)
                orow[wd * 64 + fd * 16 + l15] = acc[fm][fd][rg] * inv;
        }
}

// ---------------- fallback (proven round-2 kernel) if ws too small ----------------
#define VT_IDX(d, j) ((d)*VROW + (((((j) >> 3) ^ (((d) >> 2) & 7))) << 3) + ((j) & 7))

__global__ __launch_bounds__(512, 2)
void xattn_fallback(const float* __restrict__ S1, const float* __restrict__ S2,
                    float* __restrict__ out)
{
    __shared__ short Yh[BJ][PADD];
    __shared__ short Yl[BJ][PADD];
    __shared__ short Pt[BM][PADJ];
    __shared__ short Vt[DIM * VROW];
    __shared__ float maxpart[2][BM];
    __shared__ float spart[2][BM];
    __shared__ float runm[BM];
    __shared__ float runs[BM];
    __shared__ float fac[BM];

    const int tid  = threadIdx.x;
    const int lane = tid & 63;
    const int wave = tid >> 6;
    const int l15  = lane & 15;
    const int lg   = lane >> 4;
    const int wj   = wave >> 2;
    const int wi   = wave & 3;
    const int wi2  = wave >> 1;
    const int wd   = wave & 1;

    const int bx   = blockIdx.x;
    const int xcd  = bx & 7;
    const int slot = bx >> 3;
    const int g    = xcd * 2 + (slot >> 4);
    const int rt   = slot & 15;
    const int side = g >> 3;
    const int bb   = g & 7;

    const float* X = side ? S2 : S1;
    const float* Y = side ? S1 : S2;
    float* O = out + (size_t)side * (size_t)NBATCH * LSEQ * DIM;
    const float* Xg = X + ((size_t)bb * LSEQ + (size_t)rt * BM) * DIM;
    const float* Yg = Y + (size_t)bb * LSEQ * DIM;

    v8s xh[2][4], xl[2][4];
    #pragma unroll
    for (int fi = 0; fi < 2; ++fi) {
        const int row = wi * 32 + fi * 16 + l15;
        #pragma unroll
        for (int ks = 0; ks < 4; ++ks) {
            const int col = ks * 32 + lg * 8;
            float4 a = *(const float4*)(Xg + (size_t)row * DIM + col);
            float4 b = *(const float4*)(Xg + (size_t)row * DIM + col + 4);
            v8s h, l;
            short t;
            t = f2bf(a.x); h[0] = t; l[0] = f2bf(a.x - bf2f(t));
            t = f2bf(a.y); h[1] = t; l[1] = f2bf(a.y - bf2f(t));
            t = f2bf(a.z); h[2] = t; l[2] = f2bf(a.z - bf2f(t));
            t = f2bf(a.w); h[3] = t; l[3] = f2bf(a.w - bf2f(t));
            t = f2bf(b.x); h[4] = t; l[4] = f2bf(b.x - bf2f(t));
            t = f2bf(b.y); h[5] = t; l[5] = f2bf(b.y - bf2f(t));
            t = f2bf(b.z); h[6] = t; l[6] = f2bf(b.z - bf2f(t));
            t = f2bf(b.w); h[7] = t; l[7] = f2bf(b.w - bf2f(t));
            xh[fi][ks] = h; xl[fi][ks] = l;
        }
    }

    if (tid < BM) { runm[tid] = -INFINITY; runs[tid] = 0.f; }

    int rI[4], cI[4];
    #pragma unroll
    for (int it = 0; it < 4; ++it) {
        int idx = tid + it * 512;
        rI[it] = idx >> 5;
        cI[it] = (idx & 31) * 4;
    }
    float4 pre[4];
    #pragma unroll
    for (int it = 0; it < 4; ++it)
        pre[it] = *(const float4*)(Yg + (size_t)rI[it] * DIM + cI[it]);

    v4f acc[2][4];
    #pragma unroll
    for (int fm = 0; fm < 2; ++fm)
        #pragma unroll
        for (int fd = 0; fd < 4; ++fd)
            acc[fm][fd] = (v4f){0.f, 0.f, 0.f, 0.f};

    for (int jt = 0; jt < NJT; ++jt) {
        __syncthreads();
        #pragma unroll
        for (int it = 0; it < 4; ++it) {
            float4 v = pre[it];
            const int r = rI[it], c = cI[it];
            short h0 = f2bf(v.x), h1 = f2bf(v.y), h2 = f2bf(v.z), h3 = f2bf(v.w);
            short q0 = f2bf(v.x - bf2f(h0)), q1 = f2bf(v.y - bf2f(h1));
            short q2 = f2bf(v.z - bf2f(h2)), q3 = f2bf(v.w - bf2f(h3));
            *(short4*)&Yh[r][c] = make_short4(h0, h1, h2, h3);
            *(short4*)&Yl[r][c] = make_short4(q0, q1, q2, q3);
            Vt[VT_IDX(c + 0, r)] = h0;
            Vt[VT_IDX(c + 1, r)] = h1;
            Vt[VT_IDX(c + 2, r)] = h2;
            Vt[VT_IDX(c + 3, r)] = h3;
        }
        if (jt + 1 < NJT) {
            #pragma unroll
            for (int it = 0; it < 4; ++it)
                pre[it] = *(const float4*)(Yg + (size_t)((jt + 1) * BJ + rI[it]) * DIM + cI[it]);
        }
        __syncthreads();

        v4f e[2][2];
        #pragma unroll
        for (int fj = 0; fj < 2; ++fj)
            #pragma unroll
            for (int fi = 0; fi < 2; ++fi)
                e[fj][fi] = (v4f){0.f, 0.f, 0.f, 0.f};
        #pragma unroll
        for (int ks = 0; ks < 4; ++ks) {
            const int k0 = ks * 32 + lg * 8;
            v8s yh2[2], yl2[2];
            #pragma unroll
            for (int fj = 0; fj < 2; ++fj) {
                const int jr = wj * 32 + fj * 16 + l15;
                yh2[fj] = *(const v8s*)&Yh[jr][k0];
                yl2[fj] = *(const v8s*)&Yl[jr][k0];
            }
            #pragma unroll
            for (int fj = 0; fj < 2; ++fj)
                #pragma unroll
                for (int fi = 0; fi < 2; ++fi) {
                    e[fj][fi] = __builtin_amdgcn_mfma_f32_16x16x32_bf16(yh2[fj], xh[fi][ks], e[fj][fi], 0, 0, 0);
                    e[fj][fi] = __builtin_amdgcn_mfma_f32_16x16x32_bf16(yh2[fj], xl[fi][ks], e[fj][fi], 0, 0, 0);
                    e[fj][fi] = __builtin_amdgcn_mfma_f32_16x16x32_bf16(yl2[fj], xh[fi][ks], e[fj][fi], 0, 0, 0);
                }
        }

        #pragma unroll
        for (int fi = 0; fi < 2; ++fi) {
            float m = -INFINITY;
            #pragma unroll
            for (int fj = 0; fj < 2; ++fj)
                #pragma unroll
                for (int rg = 0; rg < 4; ++rg)
                    m = fmaxf(m, e[fj][fi][rg]);
            m = fmaxf(m, __shfl_xor(m, 16));
            m = fmaxf(m, __shfl_xor(m, 32));
            if (lg == 0) maxpart[wj][wi * 32 + fi * 16 + l15] = m;
        }
        __syncthreads();

        if (tid < BM) {
            float rs = runs[tid];
            if (jt > 0) rs += spart[0][tid] + spart[1][tid];
            float mt = fmaxf(maxpart[0][tid], maxpart[1][tid]);
            float mo = runm[tid];
            float f = 1.0f;
            if (mt > mo + THR_DEFER) { f = __expf(mo - mt); runm[tid] = mt; rs *= f; }
            fac[tid] = f;
            runs[tid] = rs;
        }
        __syncthreads();

        {
            float fr[2][4];
            bool need = false;
            #pragma unroll
            for (int fm = 0; fm < 2; ++fm)
                #pragma unroll
                for (int rg = 0; rg < 4; ++rg) {
                    fr[fm][rg] = fac[wi2 * 32 + fm * 16 + lg * 4 + rg];
                    need = need || (fr[fm][rg] != 1.0f);
                }
            if (__any(need)) {
                #pragma unroll
                for (int fm = 0; fm < 2; ++fm)
                    #pragma unroll
                    for (int fd = 0; fd < 4; ++fd)
                        #pragma unroll
                        for (int rg = 0; rg < 4; ++rg)
                            acc[fm][fd][rg] *= fr[fm][rg];
            }
        }

        #pragma unroll
        for (int fi = 0; fi < 2; ++fi) {
            const int ic = wi * 32 + fi * 16 + l15;
            const float m = runm[ic];
            float s = 0.f;
            #pragma unroll
            for (int fj = 0; fj < 2; ++fj) {
                float p0 = __expf(e[fj][fi][0] - m);
                float p1 = __expf(e[fj][fi][1] - m);
                float p2 = __expf(e[fj][fi][2] - m);
                float p3 = __expf(e[fj][fi][3] - m);
                s += p0 + p1 + p2 + p3;
                *(short4*)&Pt[ic][wj * 32 + fj * 16 + lg * 4] =
                    make_short4(f2bf(p0), f2bf(p1), f2bf(p2), f2bf(p3));
            }
            s += __shfl_xor(s, 16);
            s += __shfl_xor(s, 32);
            if (lg == 0) spart[wj][ic] = s;
        }
        __syncthreads();

        #pragma unroll
        for (int ks = 0; ks < 2; ++ks) {
            const int k0 = ks * 32 + lg * 8;
            v8s pa[2], vb[4];
            #pragma unroll
            for (int fm = 0; fm < 2; ++fm)
                pa[fm] = *(const v8s*)&Pt[wi2 * 32 + fm * 16 + l15][k0];
            #pragma unroll
            for (int fd = 0; fd < 4; ++fd) {
                const int d = wd * 64 + fd * 16 + l15;
                vb[fd] = *(const v8s*)&Vt[VT_IDX(d, k0)];
            }
            #pragma unroll
            for (int fm = 0; fm < 2; ++fm)
                #pragma unroll
                for (int fd = 0; fd < 4; ++fd)
                    acc[fm][fd] = __builtin_amdgcn_mfma_f32_16x16x32_bf16(pa[fm], vb[fd], acc[fm][fd], 0, 0, 0);
        }
    }

    __syncthreads();
    if (tid < BM) {
        float rs = runs[tid] + spart[0][tid] + spart[1][tid];
        fac[tid] = 1.0f / rs;
    }
    __syncthreads();

    #pragma unroll
    for (int fm = 0; fm < 2; ++fm)
        #pragma unroll
        for (int rg = 0; rg < 4; ++rg) {
            const int ir = wi2 * 32 + fm * 16 + lg * 4 + rg;
            const float inv = fac[ir];
            float* orow = O + ((size_t)bb * LSEQ + (size_t)rt * BM + ir) * DIM;
            #pragma unroll
            for (int fd = 0; fd < 4; ++fd)
                orow[wd * 64 + fd * 16 + l15] = acc[fm][fd][rg] * inv;
        }
}

extern "C" void kernel_launch(void* const* d_in, const int* in_sizes, int n_in,
                              void* d_out, int out_size, void* d_ws, size_t ws_size,
                              hipStream_t stream) {
    const float* s1 = (const float*)d_in[0];
    const float* s2 = (const float*)d_in[1];
    float* out = (float*)d_out;
    const size_t need = (size_t)6 * PLANE * sizeof(short);   // 24 MiB
    if (ws_size >= need && d_ws != nullptr) {
        short* ws = (short*)d_ws;
        prepass_kernel<<<dim3(LSEQ / 64, NBATCH, 2), 256, 0, stream>>>(s1, s2, ws);
        xattn_main<<<dim3(256), 512, 0, stream>>>(ws, out);
    } else {
        xattn_fallback<<<dim3(256), 512, 0, stream>>>(s1, s2, out);
    }
}

// Round 6
// 96.545 us; speedup vs baseline: 1.7828x; 1.7828x over previous
//
#include <hip/hip_runtime.h>
#include <hip/hip_bf16.h>
#include <math.h>

// Bidirectional cross-attention (B=8, L=2048, D=128, fp32 in/out).
// v5b: fp16 path. Prepass -> fp16 planes {hi, lo, tr-hi} per tensor in d_ws.
// Main: one-pass flash, 32x32x16 f16 MFMA, 2-pass E (X hi+lo regs, Y fp16),
// whole-row-per-wave (lane owns one output row): in-register softmax,
// P stays in registers (cvt_pkrtz + shfl_xor(32) D->A relayout),
// global_load_lds staging with inverse-swizzled source, ONE barrier/tile.

#define LSEQ 2048
#define DIM  128
#define NBATCH 8
#define BM 128            // X rows per block (4 waves x 32 rows)
#define BJ 64             // j-tile
#define NJT (LSEQ / BJ)   // 32
#define THR_DEFER 8.0f
#define PLANE (NBATCH * LSEQ * DIM)   // 2097152 elems (4 MiB as fp16)

typedef _Float16 halfT;
typedef halfT v8h  __attribute__((ext_vector_type(8)));
typedef float v16f __attribute__((ext_vector_type(16)));
typedef unsigned v4u __attribute__((ext_vector_type(4)));

__device__ __forceinline__ unsigned pk2u(float a, float b) {
    auto p = __builtin_amdgcn_cvt_pkrtz(a, b);   // __fp16 ext_vector(2)
    return __builtin_bit_cast(unsigned, p);
}

__device__ __forceinline__ void gload16(const void* g, void* l) {
    __builtin_amdgcn_global_load_lds(
        (const __attribute__((address_space(1))) unsigned int*)g,
        (__attribute__((address_space(3))) unsigned int*)l, 16, 0, 0);
}

__device__ __forceinline__ v16f vz16() {
    v16f z;
    #pragma unroll
    for (int r = 0; r < 16; ++r) z[r] = 0.f;
    return z;
}

// ---------------- prepass: fp32 -> {hi, lo, tr-hi} fp16 planes ----------------
__global__ __launch_bounds__(256, 4)
void prepass_kernel(const float* __restrict__ S1, const float* __restrict__ S2,
                    short* __restrict__ ws)
{
    __shared__ short Th[DIM][66];   // transposed hi tile [d][r]
    const int lt = blockIdx.x;      // l-tile (64 rows)
    const int bb = blockIdx.y;
    const int tn = blockIdx.z;      // tensor 0=S1, 1=S2
    const float* src = (tn ? S2 : S1) + ((size_t)bb * LSEQ + (size_t)lt * 64) * DIM;
    short* hi = ws + (size_t)tn * 3 * PLANE + ((size_t)bb * LSEQ + (size_t)lt * 64) * DIM;
    short* lo = hi + PLANE;
    short* tr = ws + (size_t)tn * 3 * PLANE + 2 * (size_t)PLANE
              + (size_t)bb * DIM * LSEQ + (size_t)lt * 64;
    const int tid = threadIdx.x;
    #pragma unroll
    for (int it = 0; it < 8; ++it) {
        int idx = tid + it * 256;       // 2048 float4 = 64x128 floats
        int r = idx >> 5;               // 0..63
        int c = (idx & 31) * 4;         // 0..124
        float4 v = *(const float4*)(src + (size_t)r * DIM + c);
        halfT h0 = (halfT)v.x, h1 = (halfT)v.y, h2 = (halfT)v.z, h3 = (halfT)v.w;
        halfT q0 = (halfT)(v.x - (float)h0), q1 = (halfT)(v.y - (float)h1);
        halfT q2 = (halfT)(v.z - (float)h2), q3 = (halfT)(v.w - (float)h3);
        short b0 = __builtin_bit_cast(short, h0), b1 = __builtin_bit_cast(short, h1);
        short b2 = __builtin_bit_cast(short, h2), b3 = __builtin_bit_cast(short, h3);
        *(short4*)&hi[(size_t)r * DIM + c] = make_short4(b0, b1, b2, b3);
        *(short4*)&lo[(size_t)r * DIM + c] = make_short4(
            __builtin_bit_cast(short, q0), __builtin_bit_cast(short, q1),
            __builtin_bit_cast(short, q2), __builtin_bit_cast(short, q3));
        Th[c + 0][r] = b0; Th[c + 1][r] = b1;
        Th[c + 2][r] = b2; Th[c + 3][r] = b3;
    }
    __syncthreads();
    #pragma unroll
    for (int it = 0; it < 16; ++it) {
        int idx = tid + it * 256;       // 128x32 ints
        int d = idx >> 5;
        int c = (idx & 31) * 2;
        unsigned val = (unsigned)(unsigned short)Th[d][c]
                     | ((unsigned)(unsigned short)Th[d][c + 1] << 16);
        *(unsigned*)(tr + (size_t)d * LSEQ + c) = val;
    }
}

// ---------------- main flash kernel ----------------
__global__ __launch_bounds__(256, 1)
void xattn_main(const short* __restrict__ ws, float* __restrict__ out)
{
    __shared__ short YhL[2][BJ * DIM];   // Y tile fp16 [64][128], swz ^(j&15)<<4
    __shared__ short VtL[2][DIM * BJ];   // Y^T tile fp16 [128][64], swz ^(d&7)<<4
    __shared__ float facL[4][32];        // per-wave row factors

    const int tid  = threadIdx.x;
    const int lane = tid & 63;
    const int wv   = tid >> 6;      // 0..3; wave owns rows wv*32..+31
    const int li   = lane & 31;
    const int h    = lane >> 5;     // k-half
    const int swzY = (lane & 15) << 4;
    const int swzV = (lane & 7) << 4;

    // XCD-grouped decode: 16 blocks sharing one (side,batch) Y-stream per XCD.
    const int bx   = blockIdx.x;
    const int xcd  = bx & 7;
    const int slot = bx >> 3;               // 0..31
    const int g    = xcd * 2 + (slot >> 4); // 0..15
    const int rt   = slot & 15;
    const int side = g >> 3;
    const int bb   = g & 7;

    const short* XHg = ws + (size_t)side * 3 * PLANE + ((size_t)bb * LSEQ + (size_t)rt * BM) * DIM;
    const short* XLg = XHg + PLANE;
    const short* YHg = ws + (size_t)(side ^ 1) * 3 * PLANE + (size_t)bb * LSEQ * DIM;
    const short* YTg = ws + (size_t)(side ^ 1) * 3 * PLANE + 2 * (size_t)PLANE + (size_t)bb * DIM * LSEQ;
    float* O = out + (size_t)side * PLANE + ((size_t)bb * LSEQ + (size_t)rt * BM) * DIM;

    // ---- X fragments -> regs (hi + lo fp16), loop-invariant ----
    // B-operand of 32x32x16: lane: col i = li, k = h*8 + e
    v8h xh[8], xl[8];
    {
        const size_t row = (size_t)(wv * 32 + li);
        #pragma unroll
        for (int ks = 0; ks < 8; ++ks) {
            xh[ks] = *(const v8h*)(const void*)(XHg + row * DIM + ks * 16 + h * 8);
            xl[ks] = *(const v8h*)(const void*)(XLg + row * DIM + ks * 16 + h * 8);
        }
    }

    float runm = -INFINITY, runs = 0.f;

    // staging: 8 global_load_lds per wave per tile (linear LDS dest,
    // inverse-swizzled global source).
    auto STAGE = [&](int jt, int b) {
        #pragma unroll
        for (int k = 0; k < 4; ++k) {
            const int c   = wv * 4 + k;            // Y chunk: 4 rows x 256B
            const int row = c * 4 + (lane >> 4);
            const int cb  = ((lane & 15) * 16) ^ ((row & 15) << 4);
            gload16((const char*)YHg + ((size_t)(jt * BJ + row)) * 256 + cb,
                    (char*)&YhL[b][0] + c * 1024);
        }
        #pragma unroll
        for (int k = 0; k < 4; ++k) {
            const int c = wv * 4 + k;              // Vt chunk: 8 rows x 128B
            const int d = c * 8 + (lane >> 3);
            const int cb = ((lane & 7) * 16) ^ ((d & 7) << 4);
            gload16((const char*)YTg + (size_t)d * (LSEQ * 2) + (size_t)jt * 128 + cb,
                    (char*)&VtL[b][0] + c * 1024);
        }
    };

    v16f o0 = vz16(), o1 = vz16(), o2 = vz16(), o3 = vz16();

    STAGE(0, 0);
    __syncthreads();    // prologue: full drain once

    for (int jt = 0; jt < NJT; ++jt) {
        const int cur = jt & 1;
        if (jt + 1 < NJT) STAGE(jt + 1, cur ^ 1);   // fly during compute
        const char* Yc = (const char*)&YhL[cur][0];
        const char* Vc = (const char*)&VtL[cur][0];

        // ---- E^T = Y X^T: A=Y (j rows), B=X (i cols); 4 chains ----
        v16f eH0 = vz16(), eH1 = vz16(), eL0 = vz16(), eL1 = vz16();
        #pragma unroll
        for (int ks = 0; ks < 8; ++ks) {
            const int cb = (ks * 32 + h * 16) ^ swzY;
            v8h ya0 = *(const v8h*)(Yc + (li) * 256 + cb);
            v8h ya1 = *(const v8h*)(Yc + (32 + li) * 256 + cb);
            eH0 = __builtin_amdgcn_mfma_f32_32x32x16_f16(ya0, xh[ks], eH0, 0, 0, 0);
            eH1 = __builtin_amdgcn_mfma_f32_32x32x16_f16(ya1, xh[ks], eH1, 0, 0, 0);
            eL0 = __builtin_amdgcn_mfma_f32_32x32x16_f16(ya0, xl[ks], eL0, 0, 0, 0);
            eL1 = __builtin_amdgcn_mfma_f32_32x32x16_f16(ya1, xl[ks], eL1, 0, 0, 0);
        }
        v16f p0 = eH0 + eL0;
        v16f p1 = eH1 + eL1;

        // ---- row stats (lane owns one row i = wv*32+li; pair l,l+32) ----
        float mt;
        {
            float a = fmaxf(p0[0], p0[1]);
            #pragma unroll
            for (int r = 2; r < 16; ++r) a = fmaxf(a, p0[r]);
            #pragma unroll
            for (int r = 0; r < 16; ++r) a = fmaxf(a, p1[r]);
            mt = fmaxf(a, __shfl_xor(a, 32));
        }
        float f = 1.0f;
        if (mt > runm + THR_DEFER) { f = __expf(runm - mt); runm = mt; runs *= f; }
        if (lane < 32) facL[wv][lane] = f;
        const bool anyr = __any(f != 1.0f);

        // ---- P = exp(E - m) in-register; sum ----
        float s = 0.f;
        #pragma unroll
        for (int r = 0; r < 16; ++r) { p0[r] = __expf(p0[r] - runm); s += p0[r]; }
        #pragma unroll
        for (int r = 0; r < 16; ++r) { p1[r] = __expf(p1[r] - runm); s += p1[r]; }
        s += __shfl_xor(s, 32);
        runs += s;

        // ---- acc rescale (rare: defer-max) ----
        if (anyr) {
            #pragma unroll
            for (int r = 0; r < 16; ++r) {
                const float fr = facL[wv][(r & 3) + 8 * (r >> 2) + 4 * h];
                o0[r] *= fr; o1[r] *= fr; o2[r] *= fr; o3[r] *= fr;
            }
        }

        // ---- PV: O[i][d] += P[i][j] V[j][d]; P via D->A half-swap ----
        #pragma unroll
        for (int w = 0; w < 4; ++w) {
            const v16f& P = (w < 2) ? p0 : p1;
            const int base = (w & 1) * 8;
            unsigned kA0 = pk2u(P[base + 0], P[base + 1]);
            unsigned kA1 = pk2u(P[base + 2], P[base + 3]);
            unsigned kB0 = pk2u(P[base + 4], P[base + 5]);
            unsigned kB1 = pk2u(P[base + 6], P[base + 7]);
            unsigned r0 = (unsigned)__shfl_xor((int)(h ? kA0 : kB0), 32);
            unsigned r1 = (unsigned)__shfl_xor((int)(h ? kA1 : kB1), 32);
            v4u U;
            U[0] = h ? r0 : kA0;
            U[1] = h ? r1 : kA1;
            U[2] = h ? kB0 : r0;
            U[3] = h ? kB1 : r1;
            v8h pa = __builtin_bit_cast(v8h, U);
            const int cb = (w * 32 + h * 16);
            v8h vb0 = *(const v8h*)(Vc + (0 * 32 + li) * 128 + (cb ^ swzV));
            v8h vb1 = *(const v8h*)(Vc + (1 * 32 + li) * 128 + (cb ^ swzV));
            v8h vb2 = *(const v8h*)(Vc + (2 * 32 + li) * 128 + (cb ^ swzV));
            v8h vb3 = *(const v8h*)(Vc + (3 * 32 + li) * 128 + (cb ^ swzV));
            o0 = __builtin_amdgcn_mfma_f32_32x32x16_f16(pa, vb0, o0, 0, 0, 0);
            o1 = __builtin_amdgcn_mfma_f32_32x32x16_f16(pa, vb1, o1, 0, 0, 0);
            o2 = __builtin_amdgcn_mfma_f32_32x32x16_f16(pa, vb2, o2, 0, 0, 0);
            o3 = __builtin_amdgcn_mfma_f32_32x32x16_f16(pa, vb3, o3, 0, 0, 0);
        }

        asm volatile("s_waitcnt vmcnt(0) lgkmcnt(0)" ::: "memory");
        __builtin_amdgcn_s_barrier();
        __builtin_amdgcn_sched_barrier(0);
    }

    // ---- finalize: 1/s broadcast via facL, write out ----
    if (lane < 32) facL[wv][lane] = 1.0f / runs;
    #pragma unroll
    for (int r = 0; r < 16; ++r) {
        const int ir = (r & 3) + 8 * (r >> 2) + 4 * h;
        const float inv = facL[wv][ir];
        float* orow = O + (size_t)(wv * 32 + ir) * DIM;
        orow[0 * 32 + li] = o0[r] * inv;
        orow[1 * 32 + li] = o1[r] * inv;
        orow[2 * 32 + li] = o2[r] * inv;
        orow[3 * 32 + li] = o3[r] * inv;
    }
}

extern "C" void kernel_launch(void* const* d_in, const int* in_sizes, int n_in,
                              void* d_out, int out_size, void* d_ws, size_t ws_size,
                              hipStream_t stream) {
    const float* s1 = (const float*)d_in[0];
    const float* s2 = (const float*)d_in[1];
    float* out = (float*)d_out;
    short* ws = (short*)d_ws;   // 6 * PLANE * 2B = 24 MiB
    prepass_kernel<<<dim3(LSEQ / 64, NBATCH, 2), 256, 0, stream>>>(s1, s2, ws);
    xattn_main<<<dim3(256), 256, 0, stream>>>(ws, out);
}

// Round 8
// 82.445 us; speedup vs baseline: 2.0877x; 1.1710x over previous
//
#include <hip/hip_runtime.h>
#include <hip/hip_bf16.h>
#include <math.h>

// Bidirectional cross-attention (B=8, L=2048, D=128, fp32 in/out).
// v7b: fp16 path, 8-wave blocks (2 waves/SIMD). Wave (wv,wh) owns rows
// wv*32..+31 and j-half wh: independent online softmax per wave, flash
// merge across the wave pair at the end. One barrier per j-tile.

#define LSEQ 2048
#define DIM  128
#define NBATCH 8
#define BM 128            // X rows per block (4 row-groups x 32)
#define BJ 64             // j-tile (2 halves of 32)
#define NJT (LSEQ / BJ)   // 32
#define THR_DEFER 8.0f
#define PLANE (NBATCH * LSEQ * DIM)   // 2097152 elems (4 MiB as fp16)

typedef _Float16 halfT;
typedef halfT v8h  __attribute__((ext_vector_type(8)));
typedef float v16f __attribute__((ext_vector_type(16)));
typedef unsigned v4u __attribute__((ext_vector_type(4)));

__device__ __forceinline__ unsigned pk2u(float a, float b) {
    auto p = __builtin_amdgcn_cvt_pkrtz(a, b);   // __fp16 ext_vector(2)
    return __builtin_bit_cast(unsigned, p);
}

__device__ __forceinline__ void gload16(const void* g, void* l) {
    __builtin_amdgcn_global_load_lds(
        (const __attribute__((address_space(1))) unsigned int*)g,
        (__attribute__((address_space(3))) unsigned int*)l, 16, 0, 0);
}

__device__ __forceinline__ v16f vz16() {
    v16f z;
    #pragma unroll
    for (int r = 0; r < 16; ++r) z[r] = 0.f;
    return z;
}

// ---------------- prepass: fp32 -> {hi, lo, tr-hi} fp16 planes ----------------
__global__ __launch_bounds__(256, 4)
void prepass_kernel(const float* __restrict__ S1, const float* __restrict__ S2,
                    short* __restrict__ ws)
{
    __shared__ short Th[DIM][66];   // transposed hi tile [d][r]
    const int lt = blockIdx.x;      // l-tile (64 rows)
    const int bb = blockIdx.y;
    const int tn = blockIdx.z;      // tensor 0=S1, 1=S2
    const float* src = (tn ? S2 : S1) + ((size_t)bb * LSEQ + (size_t)lt * 64) * DIM;
    short* hi = ws + (size_t)tn * 3 * PLANE + ((size_t)bb * LSEQ + (size_t)lt * 64) * DIM;
    short* lo = hi + PLANE;
    short* tr = ws + (size_t)tn * 3 * PLANE + 2 * (size_t)PLANE
              + (size_t)bb * DIM * LSEQ + (size_t)lt * 64;
    const int tid = threadIdx.x;
    #pragma unroll
    for (int it = 0; it < 8; ++it) {
        int idx = tid + it * 256;       // 2048 float4 = 64x128 floats
        int r = idx >> 5;               // 0..63
        int c = (idx & 31) * 4;         // 0..124
        float4 v = *(const float4*)(src + (size_t)r * DIM + c);
        halfT h0 = (halfT)v.x, h1 = (halfT)v.y, h2 = (halfT)v.z, h3 = (halfT)v.w;
        halfT q0 = (halfT)(v.x - (float)h0), q1 = (halfT)(v.y - (float)h1);
        halfT q2 = (halfT)(v.z - (float)h2), q3 = (halfT)(v.w - (float)h3);
        short b0 = __builtin_bit_cast(short, h0), b1 = __builtin_bit_cast(short, h1);
        short b2 = __builtin_bit_cast(short, h2), b3 = __builtin_bit_cast(short, h3);
        *(short4*)&hi[(size_t)r * DIM + c] = make_short4(b0, b1, b2, b3);
        *(short4*)&lo[(size_t)r * DIM + c] = make_short4(
            __builtin_bit_cast(short, q0), __builtin_bit_cast(short, q1),
            __builtin_bit_cast(short, q2), __builtin_bit_cast(short, q3));
        Th[c + 0][r] = b0; Th[c + 1][r] = b1;
        Th[c + 2][r] = b2; Th[c + 3][r] = b3;
    }
    __syncthreads();
    #pragma unroll
    for (int it = 0; it < 16; ++it) {
        int idx = tid + it * 256;       // 128x32 ints
        int d = idx >> 5;
        int c = (idx & 31) * 2;
        unsigned val = (unsigned)(unsigned short)Th[d][c]
                     | ((unsigned)(unsigned short)Th[d][c + 1] << 16);
        *(unsigned*)(tr + (size_t)d * LSEQ + c) = val;
    }
}

// ---------------- main flash kernel ----------------
__global__ __launch_bounds__(512, 2)
void xattn_main(const short* __restrict__ ws, float* __restrict__ out)
{
    // 64 KB pool: during the loop = 2x Y tile (2x16KB) + 2x Vt tile (2x16KB);
    // in the epilogue reused as OB[4][32][128] fp32 partial-O buffer.
    __shared__ char pool[65536];
    __shared__ float facL[4][2][32];       // per (row-group, j-half) row factors
    __shared__ float mEx[4][2][32], sEx[4][2][32];

    float (*OB)[32][128] = (float(*)[32][128])(void*)pool;

    const int tid  = threadIdx.x;
    const int lane = tid & 63;
    const int wave = tid >> 6;      // 0..7
    const int wv   = wave >> 1;     // row-group 0..3 (rows wv*32..+31)
    const int wh   = wave & 1;      // j-half 0..1
    const int li   = lane & 31;
    const int h    = lane >> 5;     // k-half
    const int swzV = (lane & 7) << 4;

    // XCD-grouped decode: 16 blocks sharing one (side,batch) Y-stream per XCD.
    const int bx   = blockIdx.x;
    const int xcd  = bx & 7;
    const int slot = bx >> 3;               // 0..31
    const int g    = xcd * 2 + (slot >> 4); // 0..15
    const int rt   = slot & 15;
    const int side = g >> 3;
    const int bb   = g & 7;

    const short* XHg = ws + (size_t)side * 3 * PLANE + ((size_t)bb * LSEQ + (size_t)rt * BM) * DIM;
    const short* XLg = XHg + PLANE;
    const short* YHg = ws + (size_t)(side ^ 1) * 3 * PLANE + (size_t)bb * LSEQ * DIM;
    const short* YTg = ws + (size_t)(side ^ 1) * 3 * PLANE + 2 * (size_t)PLANE + (size_t)bb * DIM * LSEQ;
    float* O = out + (size_t)side * PLANE + ((size_t)bb * LSEQ + (size_t)rt * BM) * DIM;

    // ---- X fragments -> regs (hi + lo fp16), loop-invariant ----
    v8h xh[8], xl[8];
    {
        const size_t row = (size_t)(wv * 32 + li);
        #pragma unroll
        for (int ks = 0; ks < 8; ++ks) {
            xh[ks] = *(const v8h*)(const void*)(XHg + row * DIM + ks * 16 + h * 8);
            xl[ks] = *(const v8h*)(const void*)(XLg + row * DIM + ks * 16 + h * 8);
        }
    }

    float runm = -INFINITY, runs = 0.f;

    // staging: 4 gload16 per wave per tile (16 Y chunks + 16 Vt chunks / 8 waves)
    auto STAGE = [&](int jt, int b) {
        #pragma unroll
        for (int k = 0; k < 2; ++k) {
            const int c   = wave * 2 + k;          // Y chunk: 4 rows x 256B
            const int row = c * 4 + (lane >> 4);
            const int cb  = ((lane & 15) * 16) ^ ((row & 15) << 4);
            gload16((const char*)YHg + ((size_t)(jt * BJ + row)) * 256 + cb,
                    pool + b * 16384 + c * 1024);
        }
        #pragma unroll
        for (int k = 0; k < 2; ++k) {
            const int c = wave * 2 + k;            // Vt chunk: 8 rows x 128B
            const int d = c * 8 + (lane >> 3);
            const int cb = ((lane & 7) * 16) ^ ((d & 7) << 4);
            gload16((const char*)YTg + (size_t)d * (LSEQ * 2) + (size_t)jt * 128 + cb,
                    pool + 32768 + b * 16384 + c * 1024);
        }
    };

    v16f o0 = vz16(), o1 = vz16(), o2 = vz16(), o3 = vz16();

    STAGE(0, 0);
    __syncthreads();    // prologue: full drain once

    for (int jt = 0; jt < NJT; ++jt) {
        const int cur = jt & 1;
        if (jt + 1 < NJT) STAGE(jt + 1, cur ^ 1);   // fly during compute
        const char* Yc = (const char*)pool + cur * 16384;
        const char* Vc = (const char*)pool + 32768 + cur * 16384;

        // ---- E^T slice: this wave's j32 x its i32; 2 chains (hi/lo) ----
        v16f eH = vz16(), eL = vz16();
        const int yrow = wh * 32 + li;
        __builtin_amdgcn_s_setprio(1);
        #pragma unroll
        for (int ks = 0; ks < 8; ++ks) {
            const int cb = (ks * 32 + h * 16) ^ ((li & 15) << 4);
            v8h ya = *(const v8h*)(Yc + yrow * 256 + cb);
            eH = __builtin_amdgcn_mfma_f32_32x32x16_f16(ya, xh[ks], eH, 0, 0, 0);
            eL = __builtin_amdgcn_mfma_f32_32x32x16_f16(ya, xl[ks], eL, 0, 0, 0);
        }
        __builtin_amdgcn_s_setprio(0);
        v16f p = eH + eL;

        // ---- row stats (lane owns row i = wv*32+li; fold k-halves) ----
        float a0 = fmaxf(p[0], p[1]),  a1 = fmaxf(p[2], p[3]);
        float a2 = fmaxf(p[4], p[5]),  a3 = fmaxf(p[6], p[7]);
        float a4 = fmaxf(p[8], p[9]),  a5 = fmaxf(p[10], p[11]);
        float a6 = fmaxf(p[12], p[13]), a7 = fmaxf(p[14], p[15]);
        float b0 = fmaxf(fmaxf(a0, a1), fmaxf(a2, a3));
        float b1 = fmaxf(fmaxf(a4, a5), fmaxf(a6, a7));
        float mt = fmaxf(b0, b1);
        mt = fmaxf(mt, __shfl_xor(mt, 32));

        float f = 1.0f;
        if (mt > runm + THR_DEFER) { f = __expf(runm - mt); runm = mt; runs *= f; }
        if (lane < 32) facL[wv][wh][lane] = f;
        const bool anyr = __any(f != 1.0f);

        // ---- P = exp(E - m) in-register; sum ----
        float s = 0.f;
        #pragma unroll
        for (int r = 0; r < 16; ++r) { p[r] = __expf(p[r] - runm); s += p[r]; }
        s += __shfl_xor(s, 32);
        runs += s;

        // ---- acc rescale (rare: defer-max) ----
        if (anyr) {
            #pragma unroll
            for (int r = 0; r < 16; ++r) {
                const float fr = facL[wv][wh][(r & 3) + 8 * (r >> 2) + 4 * h];
                o0[r] *= fr; o1[r] *= fr; o2[r] *= fr; o3[r] *= fr;
            }
        }

        // ---- PV over this wave's j32: P via D->A half-swap ----
        __builtin_amdgcn_s_setprio(1);
        #pragma unroll
        for (int w2 = 0; w2 < 2; ++w2) {
            const int base = w2 * 8;
            unsigned kA0 = pk2u(p[base + 0], p[base + 1]);
            unsigned kA1 = pk2u(p[base + 2], p[base + 3]);
            unsigned kB0 = pk2u(p[base + 4], p[base + 5]);
            unsigned kB1 = pk2u(p[base + 6], p[base + 7]);
            unsigned r0 = (unsigned)__shfl_xor((int)(h ? kA0 : kB0), 32);
            unsigned r1 = (unsigned)__shfl_xor((int)(h ? kA1 : kB1), 32);
            v4u U;
            U[0] = h ? r0 : kA0;
            U[1] = h ? r1 : kA1;
            U[2] = h ? kB0 : r0;
            U[3] = h ? kB1 : r1;
            v8h pa = __builtin_bit_cast(v8h, U);
            const int cb = (wh * 2 + w2) * 32 + h * 16;
            v8h vb0 = *(const v8h*)(Vc + (0 * 32 + li) * 128 + (cb ^ swzV));
            v8h vb1 = *(const v8h*)(Vc + (1 * 32 + li) * 128 + (cb ^ swzV));
            v8h vb2 = *(const v8h*)(Vc + (2 * 32 + li) * 128 + (cb ^ swzV));
            v8h vb3 = *(const v8h*)(Vc + (3 * 32 + li) * 128 + (cb ^ swzV));
            o0 = __builtin_amdgcn_mfma_f32_32x32x16_f16(pa, vb0, o0, 0, 0, 0);
            o1 = __builtin_amdgcn_mfma_f32_32x32x16_f16(pa, vb1, o1, 0, 0, 0);
            o2 = __builtin_amdgcn_mfma_f32_32x32x16_f16(pa, vb2, o2, 0, 0, 0);
            o3 = __builtin_amdgcn_mfma_f32_32x32x16_f16(pa, vb3, o3, 0, 0, 0);
        }
        __builtin_amdgcn_s_setprio(0);

        asm volatile("s_waitcnt vmcnt(0) lgkmcnt(0)" ::: "memory");
        __builtin_amdgcn_s_barrier();
        __builtin_amdgcn_sched_barrier(0);
    }

    // ---- epilogue: flash-merge the two j-halves of each row-group ----
    if (lane < 32) { mEx[wv][wh][lane] = runm; sEx[wv][wh][lane] = runs; }
    __syncthreads();
    if (lane < 32) {
        float m0 = mEx[wv][0][lane], m1 = mEx[wv][1][lane];
        float mM = fmaxf(m0, m1);
        float e0 = __expf(m0 - mM), e1 = __expf(m1 - mM);
        float inv = 1.0f / (sEx[wv][0][lane] * e0 + sEx[wv][1][lane] * e1);
        facL[wv][wh][lane] = (wh ? e1 : e0) * inv;
    }
    __syncthreads();
    // scale own partial O
    #pragma unroll
    for (int r = 0; r < 16; ++r) {
        const float fr = facL[wv][wh][(r & 3) + 8 * (r >> 2) + 4 * h];
        o0[r] *= fr; o1[r] *= fr; o2[r] *= fr; o3[r] *= fr;
    }
    __syncthreads();   // all tile reads long done; pool becomes OB
    if (wh == 1) {
        #pragma unroll
        for (int r = 0; r < 16; ++r) {
            const int ir = (r & 3) + 8 * (r >> 2) + 4 * h;
            OB[wv][ir][0 * 32 + li] = o0[r];
            OB[wv][ir][1 * 32 + li] = o1[r];
            OB[wv][ir][2 * 32 + li] = o2[r];
            OB[wv][ir][3 * 32 + li] = o3[r];
        }
    }
    __syncthreads();
    if (wh == 0) {
        #pragma unroll
        for (int r = 0; r < 16; ++r) {
            const int ir = (r & 3) + 8 * (r >> 2) + 4 * h;
            float* orow = O + (size_t)(wv * 32 + ir) * DIM;
            orow[0 * 32 + li] = o0[r] + OB[wv][ir][0 * 32 + li];
            orow[1 * 32 + li] = o1[r] + OB[wv][ir][1 * 32 + li];
            orow[2 * 32 + li] = o2[r] + OB[wv][ir][2 * 32 + li];
            orow[3 * 32 + li] = o3[r] + OB[wv][ir][3 * 32 + li];
        }
    }
}

extern "C" void kernel_launch(void* const* d_in, const int* in_sizes, int n_in,
                              void* d_out, int out_size, void* d_ws, size_t ws_size,
                              hipStream_t stream) {
    const float* s1 = (const float*)d_in[0];
    const float* s2 = (const float*)d_in[1];
    float* out = (float*)d_out;
    short* ws = (short*)d_ws;   // 6 * PLANE * 2B = 24 MiB
    prepass_kernel<<<dim3(LSEQ / 64, NBATCH, 2), 256, 0, stream>>>(s1, s2, ws);
    xattn_main<<<dim3(256), 512, 0, stream>>>(ws, out);
}